// Round 9
// baseline (180.053 us; speedup 1.0000x reference)
//
#include <hip/hip_runtime.h>
#include <hip/hip_bf16.h>

typedef __attribute__((ext_vector_type(8))) short bf16x8;
typedef __attribute__((ext_vector_type(4))) float f32x4;
typedef __attribute__((ext_vector_type(16))) float f32x16;
typedef __attribute__((ext_vector_type(4))) ushort u16x4;

#define AS1 __attribute__((address_space(1)))
#define AS3 __attribute__((address_space(3)))

static __device__ __forceinline__ ushort f2b(float f) {
    union { float f; unsigned u; } v;
    v.f = f;
    unsigned r = v.u + 0x7FFF + ((v.u >> 16) & 1);
    return (ushort)(r >> 16);
}

// ---------------- fused f32 -> bf16 conversion (x, Wq, Wkv, Wo) ----------------
__global__ __launch_bounds__(256) void cvt_all(const float* __restrict__ x,
                                               const float* __restrict__ Wq,
                                               const float* __restrict__ Wkv,
                                               const float* __restrict__ Wo,
                                               ushort* __restrict__ xb,
                                               ushort* __restrict__ wqkvb,
                                               ushort* __restrict__ wob)
{
    int i = blockIdx.x * blockDim.x + threadIdx.x;
    const int stride = gridDim.x * blockDim.x;
    for (; i < 4325376; i += stride) {
        const float4* src; ushort4* dst; int j;
        if (i < 2097152)      { src = (const float4*)x;   dst = (ushort4*)xb;              j = i; }
        else if (i < 3145728) { src = (const float4*)Wq;  dst = (ushort4*)wqkvb;           j = i - 2097152; }
        else if (i < 3276800) { src = (const float4*)Wkv; dst = (ushort4*)wqkvb + 1048576; j = i - 3145728; }
        else                  { src = (const float4*)Wo;  dst = (ushort4*)wob;             j = i - 3276800; }
        float4 v = src[j];
        ushort4 o; o.x = f2b(v.x); o.y = f2b(v.y); o.z = f2b(v.z); o.w = f2b(v.w);
        dst[j] = o;
    }
}

// ---------------- bf16 GEMM: C = A * B^T (r8 best bt: BK=64 dbuf, 4 waves) ------------
template<bool F32OUT>
__global__ __launch_bounds__(256) void gemm_bt(const ushort* __restrict__ A,
                                               const ushort* __restrict__ B,
                                               void* __restrict__ Cv,
                                               int M, int N, int K)
{
    __shared__ ushort As[2][128 * 64];
    __shared__ ushort Bs[2][128 * 64];
    const int tid  = threadIdx.x;
    const int lane = tid & 63;
    const int wid  = tid >> 6;
    const int l15  = lane & 15;
    const int lg   = lane >> 4;
    const int nwg8 = gridDim.x >> 3;
    const int kblk = blockIdx.x;
    const int swz  = (kblk & 7) * nwg8 + (kblk >> 3);
    const int nx   = N >> 7;
    const int brow = (swz / nx) * 128;
    const int bcol = (swz % nx) * 128;
    const int wr = wid >> 1, wc = wid & 1;

    f32x4 acc[4][4] = {};

    auto stage = [&](int bi, int k0) {
        const ushort* Ap = A + (size_t)brow * K + k0;
        const ushort* Bp = B + (size_t)bcol * K + k0;
#pragma unroll
        for (int j = 0; j < 4; ++j) {
            const int G = j * 256 + tid;
            const int r = G >> 3;
            const int s = (G & 7) ^ (r & 7);
            const int dc = (j * 256 + (wid << 6)) * 8;
            __builtin_amdgcn_global_load_lds(
                (const AS1 void*)(Ap + (size_t)r * K + s * 8),
                (AS3 void*)(&As[bi][dc]), 16, 0, 0);
            __builtin_amdgcn_global_load_lds(
                (const AS1 void*)(Bp + (size_t)r * K + s * 8),
                (AS3 void*)(&Bs[bi][dc]), 16, 0, 0);
        }
    };

    stage(0, 0);
    __syncthreads();
    int cur = 0;

    for (int k0 = 0; k0 < K; k0 += 64) {
        if (k0 + 64 < K) stage(cur ^ 1, k0 + 64);

        bf16x8 af[4][2], bfr[4][2];
#pragma unroll
        for (int m = 0; m < 4; ++m) {
            int row = wr * 64 + m * 16 + l15;
#pragma unroll
            for (int kh = 0; kh < 2; ++kh) {
                int sl = (kh * 4 + lg) ^ (row & 7);
                af[m][kh] = *(const bf16x8*)(&As[cur][row * 64 + sl * 8]);
            }
        }
#pragma unroll
        for (int n = 0; n < 4; ++n) {
            int row = wc * 64 + n * 16 + l15;
#pragma unroll
            for (int kh = 0; kh < 2; ++kh) {
                int sl = (kh * 4 + lg) ^ (row & 7);
                bfr[n][kh] = *(const bf16x8*)(&Bs[cur][row * 64 + sl * 8]);
            }
        }
#pragma unroll
        for (int m = 0; m < 4; ++m)
#pragma unroll
            for (int n = 0; n < 4; ++n) {
                acc[m][n] = __builtin_amdgcn_mfma_f32_16x16x32_bf16(af[m][0], bfr[n][0], acc[m][n], 0, 0, 0);
                acc[m][n] = __builtin_amdgcn_mfma_f32_16x16x32_bf16(af[m][1], bfr[n][1], acc[m][n], 0, 0, 0);
            }

        __syncthreads();
        cur ^= 1;
    }

#pragma unroll
    for (int m = 0; m < 4; ++m)
#pragma unroll
        for (int n = 0; n < 4; ++n) {
            int row0 = brow + wr * 64 + m * 16 + lg * 4;
            int col  = bcol + wc * 64 + n * 16 + l15;
#pragma unroll
            for (int j = 0; j < 4; ++j) {
                float v = acc[m][n][j];
                if (F32OUT)
                    ((float*)Cv)[(size_t)(row0 + j) * N + col] = v;
                else
                    ((ushort*)Cv)[(size_t)(row0 + j) * N + col] = f2b(v);
            }
        }
}

// ---------------- fused QKV projection: 256x256 8-phase, attempt #3 -------------------
// Fixes vs r2: (1) sched_barrier(0) pins ds_reads BEFORE s_barrier and MFMA AFTER
// lgkmcnt(0) (rule #18 / scheduler-sinking); (2) corrected half-tile ring + vmcnt(3)
// (r2's vmcnt(4) left P2/P3-needed halves in flight — latent race, no pipeline).
// Ring (stage -> barrier-separated last read; completes at drain before first read):
//   P1:{buf1.B1(t1)}  P2:{buf0.A0(t0+2)}  P4:{buf0.B0,A1(t0+2)}+vmcnt(3)
//   P5:{buf0.B1(t0+2)}  P6:{buf1.A0(t1+2)}  P8:{buf1.B0,A1(t1+2)}+vmcnt(3)
// Prologue: buf0{A0,B0,A1,B1}(0) + buf1{A0,B0,A1}(1) = 7 issues, vmcnt(3), barrier.
// Last iter peeled: only P1's stage remains; vmcnt(0) at its P4.
#define VMW3 asm volatile("s_waitcnt vmcnt(3)" ::: "memory")
#define VMW0 asm volatile("s_waitcnt vmcnt(0)" ::: "memory")
#define QKV_PHASE(BUF, MH, NH, STG, DRN) do {                                            \
    if (NH == 0) {                                                                       \
        _Pragma("unroll")                                                                \
        for (int m = 0; m < 4; ++m) {                                                    \
            _Pragma("unroll")                                                            \
            for (int kh = 0; kh < 2; ++kh) {                                             \
                int r  = MH * 128 + wr * 64 + m * 16 + l15;                              \
                int sl = (kh * 4 + lg) ^ (r & 7);                                        \
                af[m][kh] = *(const bf16x8*)(&Asm[BUF][r * 64 + sl * 8]);                \
            }                                                                            \
        }                                                                                \
    }                                                                                    \
    _Pragma("unroll")                                                                    \
    for (int n = 0; n < 2; ++n) {                                                        \
        _Pragma("unroll")                                                                \
        for (int kh = 0; kh < 2; ++kh) {                                                 \
            int r  = NH * 128 + wc * 32 + n * 16 + l15;                                  \
            int sl = (kh * 4 + lg) ^ (r & 7);                                            \
            bf[n][kh] = *(const bf16x8*)(&Bsm[BUF][r * 64 + sl * 8]);                    \
        }                                                                                \
    }                                                                                    \
    __builtin_amdgcn_sched_barrier(0);  /* pin ds_reads before the barrier */            \
    STG;                                                                                 \
    __builtin_amdgcn_s_barrier();                                                        \
    asm volatile("s_waitcnt lgkmcnt(0)" ::: "memory");                                   \
    __builtin_amdgcn_sched_barrier(0);  /* rule #18: MFMA must not hoist above */        \
    __builtin_amdgcn_s_setprio(1);                                                       \
    _Pragma("unroll")                                                                    \
    for (int m = 0; m < 4; ++m) {                                                        \
        _Pragma("unroll")                                                                \
        for (int n = 0; n < 2; ++n) {                                                    \
            acc[MH * 4 + m][NH * 2 + n] = __builtin_amdgcn_mfma_f32_16x16x32_bf16(       \
                af[m][0], bf[n][0], acc[MH * 4 + m][NH * 2 + n], 0, 0, 0);               \
            acc[MH * 4 + m][NH * 2 + n] = __builtin_amdgcn_mfma_f32_16x16x32_bf16(       \
                af[m][1], bf[n][1], acc[MH * 4 + m][NH * 2 + n], 0, 0, 0);               \
        }                                                                                \
    }                                                                                    \
    __builtin_amdgcn_s_setprio(0);                                                       \
    DRN;                                                                                 \
    __builtin_amdgcn_s_barrier();                                                        \
} while (0)

__global__ __launch_bounds__(512, 2) void gemm_qkv8(const ushort* __restrict__ A,
                                                    const ushort* __restrict__ B,
                                                    ushort* __restrict__ Cq,
                                                    ushort* __restrict__ Ckv,
                                                    ushort* __restrict__ Vt)
{
    constexpr int K = 2048;
    __shared__ ushort Asm[2][16384];   // [buf][256 rows][64 cols]
    __shared__ ushort Bsm[2][16384];

    const int tid  = threadIdx.x;
    const int lane = tid & 63;
    const int wid  = tid >> 6;
    const int l15  = lane & 15;
    const int lg   = lane >> 4;
    const int wr   = wid >> 2;          // 0..1 (M)
    const int wc   = wid & 3;           // 0..3 (N)
    const int bid  = blockIdx.x;
    const int swz  = (bid & 7) * 18 + (bid >> 3);   // 144 blocks, 144%8==0 bijective
    const int brow = (swz / 9) * 256;
    const int bcol = (swz % 9) * 256;

    f32x4  acc[8][4] = {};
    bf16x8 af[4][2], bf[2][2];

    // which: 0=A rows[0,128) 1=A rows[128,256) 2=B rows[0,128) 3=B rows[128,256)
    auto stageH = [&](int bi, int which, int t) {
        const int k0 = t << 6;
        const ushort* src;
        ushort* dst;
        if (which == 0)      { src = A + (size_t)brow * K + k0;         dst = &Asm[bi][0];    }
        else if (which == 1) { src = A + (size_t)(brow + 128) * K + k0; dst = &Asm[bi][8192]; }
        else if (which == 2) { src = B + (size_t)bcol * K + k0;         dst = &Bsm[bi][0];    }
        else                 { src = B + (size_t)(bcol + 128) * K + k0; dst = &Bsm[bi][8192]; }
#pragma unroll
        for (int j = 0; j < 2; ++j) {
            const int t8 = j * 512 + tid;
            const int r  = t8 >> 3;
            const int s  = (t8 & 7) ^ (r & 7);    // inverse-swizzled SOURCE, linear LDS dest
            __builtin_amdgcn_global_load_lds(
                (const AS1 void*)(src + (size_t)r * K + s * 8),
                (AS3 void*)(dst + (j * 512 + (wid << 6)) * 8), 16, 0, 0);
        }
    };

    // Prologue: buf0 complete (tile 0) + buf1 {A0,B0,A1} (tile 1). 7 issues; vmcnt(3)
    // completes exactly buf0's 4 halves. buf1.B1(1) is staged at P1 of iter 0.
    stageH(0, 0, 0); stageH(0, 2, 0); stageH(0, 1, 0); stageH(0, 3, 0);
    stageH(1, 0, 1); stageH(1, 2, 1); stageH(1, 1, 1);
    VMW3;
    __builtin_amdgcn_s_barrier();

#pragma unroll 1
    for (int i = 0; i < 15; ++i) {
        const int t1 = 2 * i + 1;
        QKV_PHASE(0, 0, 0, { stageH(1, 3, t1); },                    ((void)0));  // buf1.B1(t1)
        QKV_PHASE(0, 0, 1, { stageH(0, 0, t1 + 1); },                ((void)0));  // buf0.A0(t0+2)
        QKV_PHASE(0, 1, 0, { ((void)0); },                           ((void)0));
        QKV_PHASE(0, 1, 1, { stageH(0, 2, t1 + 1); stageH(0, 1, t1 + 1); }, VMW3); // buf0.B0,A1
        QKV_PHASE(1, 0, 0, { stageH(0, 3, t1 + 1); },                ((void)0));  // buf0.B1(t0+2)
        QKV_PHASE(1, 0, 1, { stageH(1, 0, t1 + 2); },                ((void)0));  // buf1.A0(t1+2)
        QKV_PHASE(1, 1, 0, { ((void)0); },                           ((void)0));
        QKV_PHASE(1, 1, 1, { stageH(1, 2, t1 + 2); stageH(1, 1, t1 + 2); }, VMW3); // buf1.B0,A1
    }
    // Peeled final iteration (tiles 30, 31): only buf1.B1(31) remains to stage.
    QKV_PHASE(0, 0, 0, { stageH(1, 3, 31); }, ((void)0));
    QKV_PHASE(0, 0, 1, { ((void)0); }, ((void)0));
    QKV_PHASE(0, 1, 0, { ((void)0); }, ((void)0));
    QKV_PHASE(0, 1, 1, { ((void)0); }, VMW0);
    QKV_PHASE(1, 0, 0, { ((void)0); }, ((void)0));
    QKV_PHASE(1, 0, 1, { ((void)0); }, ((void)0));
    QKV_PHASE(1, 1, 0, { ((void)0); }, ((void)0));
    QKV_PHASE(1, 1, 1, { ((void)0); }, ((void)0));

    // Epilogue: scatter to Q / K / V^T (region boundaries 16-aligned, frag-uniform)
#pragma unroll
    for (int MH = 0; MH < 2; ++MH)
#pragma unroll
    for (int m = 0; m < 4; ++m)
#pragma unroll
    for (int NH = 0; NH < 2; ++NH)
#pragma unroll
    for (int n = 0; n < 2; ++n) {
        const int row0 = brow + MH * 128 + wr * 64 + m * 16 + lg * 4;
        const int col  = bcol + NH * 128 + wc * 32 + n * 16 + l15;
        const f32x4 v4 = acc[MH * 4 + m][NH * 2 + n];
#pragma unroll
        for (int j = 0; j < 4; ++j) {
            const float v = v4[j];
            const int row = row0 + j;
            if (col < 2048) {
                Cq[(size_t)row * 2048 + col] = f2b(v);
            } else if (col < 2176) {
                Ckv[(size_t)row * 256 + (col - 2048)] = f2b(v);
            } else {
                Vt[((size_t)((row >> 11) * 128 + (col - 2176))) * 2048 + (row & 2047)] = f2b(v);
            }
        }
    }
}

// ---------------- MQA causal flash attention (r19/r20 attn12) --------------------------
__global__ __launch_bounds__(256, 2) void mqa_attn12(const ushort* __restrict__ Q,
                                                     const ushort* __restrict__ KV,
                                                     const ushort* __restrict__ Vt,
                                                     ushort* __restrict__ O)
{
    const int tid = threadIdx.x, lane = tid & 63, wid = tid >> 6;
    const int c31 = lane & 31, H = lane >> 5;
    const int bid = blockIdx.x;
    const int a  = bid & 31;
    const int hp = (bid >> 5) & 7;
    const int b  = bid >> 8;
    const int h  = hp * 2 + (wid >> 1);
    const int p  = wid & 1;

    __shared__ __align__(16) ushort SMEM[32768];  // 64 KB

    const ushort* KVb = KV + (size_t)b * 2048 * 256;
    const ushort* Vtb = Vt + (size_t)b * 128 * 2048;
    const float C2 = 0.12751763f;       // (1/sqrt(128)) * log2(e)
    const float mC = 32.0f * C2;        // fixed max (raw units)

    auto stageK = [&](int buf, int par, int t) {
        ushort* dst = SMEM + (buf * 2 + par) * 4096;
        const int kvb = t * 32;
#pragma unroll
        for (int i = 0; i < 8; ++i) {
            int G = i * 64 + lane;
            int r = G >> 4, gc = G & 15;
            int sgc = gc ^ (r & 15);
            __builtin_amdgcn_global_load_lds(
                (const AS1 void*)(KVb + (size_t)(kvb + r) * 256 + sgc * 8),
                (AS3 void*)(dst + i * 512), 16, 0, 0);
        }
    };
    auto stageV = [&](int buf, int par, int t) {
        ushort* dst = SMEM + 16384 + (buf * 2 + par) * 4096;
        const int kvb = t * 32;
#pragma unroll
        for (int i = 0; i < 8; ++i) {
            int G = i * 64 + lane;
            int g = G >> 3, s = G & 7;
            int u = s ^ (g & 7);
            int r = 2 * g + (u & 1);
            int cc = u >> 1;
            __builtin_amdgcn_global_load_lds(
                (const AS1 void*)(Vtb + (size_t)r * 2048 + kvb + cc * 8),
                (AS3 void*)(dst + G * 8), 16, 0, 0);
        }
    };

#pragma unroll 1
    for (int phase = 0; phase < 2; ++phase) {
        const int tile  = phase ? (63 - a) : a;
        const int qtile = tile * 32;
        const int U = tile + 1;
        const int S = (U + 1) >> 1;
        const size_t qrow = (size_t)(b * 2048 + qtile + c31);

        bf16x8 qf[8];
#pragma unroll
        for (int dk = 0; dk < 8; ++dk)
            qf[dk] = *(const bf16x8*)(Q + qrow * 2048 + h * 128 + dk * 16 + H * 8);

        float l_run = 0.f;
        f32x16 of[4];
#pragma unroll
        for (int dt = 0; dt < 4; ++dt)
#pragma unroll
            for (int r = 0; r < 16; ++r) of[dt][r] = 0.f;

        {
            int t = p;
            if (t < U) { if (wid < 2) stageK(0, p, t); else stageV(0, p, t); }
        }
        __syncthreads();

#pragma unroll 1
        for (int s = 0; s < S; ++s) {
            if (s + 1 < S) {
                int tn = 2 * (s + 1) + p;
                if (tn < U) { if (wid < 2) stageK((s + 1) & 1, p, tn); else stageV((s + 1) & 1, p, tn); }
            }
            const int t = 2 * s + p;
            if (t < U) {
                const ushort* Kb = SMEM + ((s & 1) * 2 + p) * 4096;
                const ushort* Vb = SMEM + 16384 + ((s & 1) * 2 + p) * 4096;
                const bool maskt = (t == tile);

                f32x16 sg = {0,0,0,0,0,0,0,0,0,0,0,0,0,0,0,0};
                __builtin_amdgcn_s_setprio(1);
#pragma unroll
                for (int dk = 0; dk < 8; ++dk) {
                    bf16x8 kf = *(const bf16x8*)(Kb + c31 * 128 + ((dk * 16 + H * 8) ^ ((c31 & 15) << 3)));
                    sg = __builtin_amdgcn_mfma_f32_32x32x16_bf16(kf, qf[dk], sg, 0, 0, 0);
                }
                __builtin_amdgcn_s_setprio(0);

                float e[16];
#pragma unroll
                for (int r = 0; r < 16; ++r) {
                    float v = sg[r];
                    if (maskt) {
                        int crow = (r & 3) + 8 * (r >> 2) + 4 * H;
                        if (crow > c31) v = -1e30f;
                    }
                    e[r] = __builtin_amdgcn_exp2f(__builtin_fmaf(v, C2, -mC));
                }
                float rsum = 0.f;
#pragma unroll
                for (int r = 0; r < 16; ++r) rsum += e[r];
                rsum += __shfl_xor(rsum, 32);
                l_run += rsum;

                unsigned pk[8];
#pragma unroll
                for (int i = 0; i < 8; ++i)
                    asm("v_cvt_pk_bf16_f32 %0, %1, %2" : "=v"(pk[i]) : "v"(e[2 * i]), "v"(e[2 * i + 1]));
                asm("v_permlane32_swap_b32 %0, %1" : "+v"(pk[0]), "+v"(pk[2]));
                asm("v_permlane32_swap_b32 %0, %1" : "+v"(pk[1]), "+v"(pk[3]));
                asm("v_permlane32_swap_b32 %0, %1" : "+v"(pk[4]), "+v"(pk[6]));
                asm("v_permlane32_swap_b32 %0, %1" : "+v"(pk[5]), "+v"(pk[7]));
                union { unsigned u[4]; bf16x8 v; } P0, P1;
                P0.u[0] = pk[0]; P0.u[1] = pk[1]; P0.u[2] = pk[2]; P0.u[3] = pk[3];
                P1.u[0] = pk[4]; P1.u[1] = pk[5]; P1.u[2] = pk[6]; P1.u[3] = pk[7];

                __builtin_amdgcn_s_setprio(1);
#pragma unroll
                for (int dt = 0; dt < 4; ++dt) {
                    int g  = dt * 16 + (c31 >> 1);
                    int sw = g & 7;
                    int b0 = c31 & 1;
                    int s0 = (2 * H + b0) ^ sw;
                    int s1 = (4 + 2 * H + b0) ^ sw;
                    bf16x8 v0 = *(const bf16x8*)(Vb + (g * 8 + s0) * 8);
                    bf16x8 v1 = *(const bf16x8*)(Vb + (g * 8 + s1) * 8);
                    of[dt] = __builtin_amdgcn_mfma_f32_32x32x16_bf16(v0, P0.v, of[dt], 0, 0, 0);
                    of[dt] = __builtin_amdgcn_mfma_f32_32x32x16_bf16(v1, P1.v, of[dt], 0, 0, 0);
                }
                __builtin_amdgcn_s_setprio(0);
            }
            __syncthreads();
        }

        // ---- merge kv-parities (fixed m -> l's simply add) ----
        float* mlb = (float*)SMEM;
        if (H == 0) mlb[wid * 32 + c31] = l_run;
        __syncthreads();
        {
            float lo = mlb[(wid ^ 1) * 32 + c31];
            float inv = 1.0f / (l_run + lo);
            float* ob = (float*)(SMEM + 512) + (wid >> 1) * 4096;
            if (p == 1) {
#pragma unroll
                for (int dt = 0; dt < 4; ++dt)
#pragma unroll
                    for (int rq = 0; rq < 4; ++rq) {
                        f32x4 w;
#pragma unroll
                        for (int j = 0; j < 4; ++j) w[j] = of[dt][rq * 4 + j];
                        *(f32x4*)(ob + ((dt * 4 + rq) * 64 + lane) * 4) = w;
                    }
            }
            __syncthreads();
            if (p == 0) {
                ushort* Orow = O + qrow * 2048 + h * 128;
#pragma unroll
                for (int dt = 0; dt < 4; ++dt)
#pragma unroll
                    for (int rq = 0; rq < 4; ++rq) {
                        f32x4 r4 = *(const f32x4*)(ob + ((dt * 4 + rq) * 64 + lane) * 4);
                        u16x4 o4;
#pragma unroll
                        for (int j = 0; j < 4; ++j)
                            o4[j] = f2b((of[dt][rq * 4 + j] + r4[j]) * inv);
                        int d0 = dt * 32 + rq * 8 + 4 * H;
                        *(u16x4*)(Orow + d0) = o4;
                    }
            }
        }
        __syncthreads();
    }
}

extern "C" void kernel_launch(void* const* d_in, const int* in_sizes, int n_in,
                              void* d_out, int out_size, void* d_ws, size_t ws_size,
                              hipStream_t stream) {
    const float* x   = (const float*)d_in[0];
    const float* Wq  = (const float*)d_in[1];
    const float* Wkv = (const float*)d_in[2];
    const float* Wo  = (const float*)d_in[3];

    char* ws = (char*)d_ws;
    ushort* xb    = (ushort*)(ws);             // [4096][2048] bf16 (16 MB); reused as aob after gemm_qkv
    ushort* wqkvb = (ushort*)(ws + 16777216);  // [2304][2048] (18 MB)
    ushort* wob   = (ushort*)(ws + 35651584);  // [2048][2048] (8 MB)
    ushort* qb    = (ushort*)(ws + 44040192);  // [4096][2048] (16 MB)
    ushort* kvb   = (ushort*)(ws + 60817408);  // [4096][256]  (2 MB, K half used)
    ushort* vtb   = (ushort*)(ws + 62914560);  // [2][128][2048] (1 MB)
    ushort* aob   = xb;                        // attn output aliases xb

    cvt_all<<<2048, 256, 0, stream>>>(x, Wq, Wkv, Wo, xb, wqkvb, wob);

    gemm_qkv8<<<144, 512, 0, stream>>>(xb, wqkvb, qb, kvb, vtb);
    mqa_attn12<<<512, 256, 0, stream>>>(qb, kvb, vtb, aob);
    gemm_bt<true><<<512, 256, 0, stream>>>(aob, wob, d_out, 4096, 2048, 2048);
}

// Round 10
// 165.596 us; speedup vs baseline: 1.0873x; 1.0873x over previous
//
#include <hip/hip_runtime.h>
#include <hip/hip_bf16.h>

typedef __attribute__((ext_vector_type(8))) short bf16x8;
typedef __attribute__((ext_vector_type(4))) float f32x4;
typedef __attribute__((ext_vector_type(16))) float f32x16;
typedef __attribute__((ext_vector_type(4))) ushort u16x4;

#define AS1 __attribute__((address_space(1)))
#define AS3 __attribute__((address_space(3)))

static __device__ __forceinline__ ushort f2b(float f) {
    union { float f; unsigned u; } v;
    v.f = f;
    unsigned r = v.u + 0x7FFF + ((v.u >> 16) & 1);
    return (ushort)(r >> 16);
}

// ---------------- fused f32 -> bf16 conversion (x, Wq, Wkv, Wo) ----------------
__global__ __launch_bounds__(256) void cvt_all(const float* __restrict__ x,
                                               const float* __restrict__ Wq,
                                               const float* __restrict__ Wkv,
                                               const float* __restrict__ Wo,
                                               ushort* __restrict__ xb,
                                               ushort* __restrict__ wqkvb,
                                               ushort* __restrict__ wob)
{
    int i = blockIdx.x * blockDim.x + threadIdx.x;
    const int stride = gridDim.x * blockDim.x;
    for (; i < 4325376; i += stride) {
        const float4* src; ushort4* dst; int j;
        if (i < 2097152)      { src = (const float4*)x;   dst = (ushort4*)xb;              j = i; }
        else if (i < 3145728) { src = (const float4*)Wq;  dst = (ushort4*)wqkvb;           j = i - 2097152; }
        else if (i < 3276800) { src = (const float4*)Wkv; dst = (ushort4*)wqkvb + 1048576; j = i - 3145728; }
        else                  { src = (const float4*)Wo;  dst = (ushort4*)wob;             j = i - 3276800; }
        float4 v = src[j];
        ushort4 o; o.x = f2b(v.x); o.y = f2b(v.y); o.z = f2b(v.z); o.w = f2b(v.w);
        dst[j] = o;
    }
}

// ---------------- bf16 GEMM: C = A * B^T (BK=64 dbuf + 8 waves, composed) -------------
// 128x128 tile, BK=64, 8 waves (2M x 4N), per-wave 64x32 (4x2 frags, 16 MFMA/K-step).
// Composition of the two measured bt wins: BK=64 (half the vmcnt(0) drains, r3/r8
// arithmetic: -7.2 us) + 8 waves (16 waves/CU during drains, r0->r4: -2.6 us).
// 64 KiB LDS, 512 blocks = exactly 2.0 blocks/CU (LDS-capped, no tail).
// LDS rows = 64 ushort = 8 x 16B slots; swizzle slot ^= (row&7) -> 2-way max (free).
// Staged via inverse-swizzled SOURCE, wave-uniform linear LDS dest (rule #21):
// chunk G = j*512+tid -> row G>>3, src slot (G&7)^(row&7), dest base j*4096+wid*512.
template<bool F32OUT>
__global__ __launch_bounds__(512) void gemm_bt(const ushort* __restrict__ A,
                                               const ushort* __restrict__ B,
                                               void* __restrict__ Cv,
                                               int M, int N, int K)
{
    __shared__ ushort As[2][128 * 64];
    __shared__ ushort Bs[2][128 * 64];
    const int tid  = threadIdx.x;
    const int lane = tid & 63;
    const int wid  = tid >> 6;
    const int l15  = lane & 15;
    const int lg   = lane >> 4;
    const int nwg8 = gridDim.x >> 3;
    const int kblk = blockIdx.x;
    const int swz  = (kblk & 7) * nwg8 + (kblk >> 3);
    const int nx   = N >> 7;
    const int brow = (swz / nx) * 128;
    const int bcol = (swz % nx) * 128;
    const int wr = wid >> 2, wc = wid & 3;

    f32x4 acc[4][2] = {};

    auto stage = [&](int bi, int k0) {
        const ushort* Ap = A + (size_t)brow * K + k0;
        const ushort* Bp = B + (size_t)bcol * K + k0;
#pragma unroll
        for (int j = 0; j < 2; ++j) {
            const int G = j * 512 + tid;           // chunk index: 128 rows x 8 slots
            const int r = G >> 3;
            const int s = (G & 7) ^ (r & 7);       // inverse-swizzled source slot
            const int dc = j * 4096 + (wid << 9);  // wave-uniform linear dest (ushorts)
            __builtin_amdgcn_global_load_lds(
                (const AS1 void*)(Ap + (size_t)r * K + s * 8),
                (AS3 void*)(&As[bi][dc]), 16, 0, 0);
            __builtin_amdgcn_global_load_lds(
                (const AS1 void*)(Bp + (size_t)r * K + s * 8),
                (AS3 void*)(&Bs[bi][dc]), 16, 0, 0);
        }
    };

    stage(0, 0);
    __syncthreads();
    int cur = 0;

    for (int k0 = 0; k0 < K; k0 += 64) {
        if (k0 + 64 < K) stage(cur ^ 1, k0 + 64);

        bf16x8 af[4][2], bfr[2][2];
#pragma unroll
        for (int m = 0; m < 4; ++m) {
            int row = wr * 64 + m * 16 + l15;
#pragma unroll
            for (int kh = 0; kh < 2; ++kh) {
                int sl = (kh * 4 + lg) ^ (row & 7);
                af[m][kh] = *(const bf16x8*)(&As[cur][row * 64 + sl * 8]);
            }
        }
#pragma unroll
        for (int n = 0; n < 2; ++n) {
            int row = wc * 32 + n * 16 + l15;
#pragma unroll
            for (int kh = 0; kh < 2; ++kh) {
                int sl = (kh * 4 + lg) ^ (row & 7);
                bfr[n][kh] = *(const bf16x8*)(&Bs[cur][row * 64 + sl * 8]);
            }
        }
#pragma unroll
        for (int m = 0; m < 4; ++m)
#pragma unroll
            for (int n = 0; n < 2; ++n) {
                acc[m][n] = __builtin_amdgcn_mfma_f32_16x16x32_bf16(af[m][0], bfr[n][0], acc[m][n], 0, 0, 0);
                acc[m][n] = __builtin_amdgcn_mfma_f32_16x16x32_bf16(af[m][1], bfr[n][1], acc[m][n], 0, 0, 0);
            }

        __syncthreads();
        cur ^= 1;
    }

#pragma unroll
    for (int m = 0; m < 4; ++m)
#pragma unroll
        for (int n = 0; n < 2; ++n) {
            int row0 = brow + wr * 64 + m * 16 + lg * 4;
            int col  = bcol + wc * 32 + n * 16 + l15;
#pragma unroll
            for (int j = 0; j < 4; ++j) {
                float v = acc[m][n][j];
                if (F32OUT)
                    ((float*)Cv)[(size_t)(row0 + j) * N + col] = v;
                else
                    ((ushort*)Cv)[(size_t)(row0 + j) * N + col] = f2b(v);
            }
        }
}

// ---------------- fused QKV projection (r4 best: 576 blocks, 8 waves, BK=32, 63.3 us) -
__global__ __launch_bounds__(512) void gemm_qkv(const ushort* __restrict__ A,
                                                const ushort* __restrict__ B,
                                                ushort* __restrict__ Cq,
                                                ushort* __restrict__ Ckv,
                                                ushort* __restrict__ Vt,
                                                int M, int K)
{
    __shared__ ushort As[2][128 * 32];
    __shared__ ushort Bs[2][128 * 32];
    const int tid  = threadIdx.x;
    const int lane = tid & 63;
    const int wid  = tid >> 6;
    const int l15  = lane & 15;
    const int lg   = lane >> 4;
    const int nwg8 = gridDim.x >> 3;
    const int kblk = blockIdx.x;
    const int swz  = (kblk & 7) * nwg8 + (kblk >> 3);
    const int brow = (swz / 18) * 128;
    const int bcol = (swz % 18) * 128;
    const int wr = wid >> 2, wc = wid & 3;

    f32x4 acc[4][2] = {};

    auto stage = [&](int bi, int k0) {
        const ushort* Ap = A + (size_t)brow * K + k0;
        const ushort* Bp = B + (size_t)bcol * K + k0;
        const int r   = tid >> 2;
        const int sgc = (tid & 3) ^ ((r >> 1) & 3);
        __builtin_amdgcn_global_load_lds(
            (const AS1 void*)(Ap + (size_t)r * K + sgc * 8),
            (AS3 void*)(&As[bi][wid * 512]), 16, 0, 0);
        __builtin_amdgcn_global_load_lds(
            (const AS1 void*)(Bp + (size_t)r * K + sgc * 8),
            (AS3 void*)(&Bs[bi][wid * 512]), 16, 0, 0);
    };

    stage(0, 0);
    __syncthreads();
    int cur = 0;

    for (int k0 = 0; k0 < K; k0 += 32) {
        if (k0 + 32 < K) stage(cur ^ 1, k0 + 32);

        bf16x8 af[4], bfr[2];
#pragma unroll
        for (int m = 0; m < 4; ++m) {
            int row = wr * 64 + m * 16 + l15;
            int slot = lg ^ ((row >> 1) & 3);
            af[m] = *(const bf16x8*)(&As[cur][row * 32 + slot * 8]);
        }
#pragma unroll
        for (int n = 0; n < 2; ++n) {
            int row = wc * 32 + n * 16 + l15;
            int slot = lg ^ ((row >> 1) & 3);
            bfr[n] = *(const bf16x8*)(&Bs[cur][row * 32 + slot * 8]);
        }
#pragma unroll
        for (int m = 0; m < 4; ++m)
#pragma unroll
            for (int n = 0; n < 2; ++n)
                acc[m][n] = __builtin_amdgcn_mfma_f32_16x16x32_bf16(af[m], bfr[n], acc[m][n], 0, 0, 0);

        __syncthreads();
        cur ^= 1;
    }

    const bool toK = (bcol == 2048);
    const bool toV = (bcol == 2176);
#pragma unroll
    for (int m = 0; m < 4; ++m)
#pragma unroll
        for (int n = 0; n < 2; ++n) {
            int row0 = brow + wr * 64 + m * 16 + lg * 4;
            int col  = bcol + wc * 32 + n * 16 + l15;
#pragma unroll
            for (int j = 0; j < 4; ++j) {
                float v = acc[m][n][j];
                int row = row0 + j;
                if (toV) {
                    int d = col - 2176;
                    int bb = row >> 11, s = row & 2047;
                    Vt[((size_t)(bb * 128 + d)) * 2048 + s] = f2b(v);
                } else if (toK) {
                    Ckv[(size_t)row * 256 + (col - 2048)] = f2b(v);
                } else {
                    Cq[(size_t)row * 2048 + col] = f2b(v);
                }
            }
        }
}

// ---------------- MQA causal flash attention (r19/r20 attn12) --------------------------
__global__ __launch_bounds__(256, 2) void mqa_attn12(const ushort* __restrict__ Q,
                                                     const ushort* __restrict__ KV,
                                                     const ushort* __restrict__ Vt,
                                                     ushort* __restrict__ O)
{
    const int tid = threadIdx.x, lane = tid & 63, wid = tid >> 6;
    const int c31 = lane & 31, H = lane >> 5;
    const int bid = blockIdx.x;
    const int a  = bid & 31;
    const int hp = (bid >> 5) & 7;
    const int b  = bid >> 8;
    const int h  = hp * 2 + (wid >> 1);
    const int p  = wid & 1;

    __shared__ __align__(16) ushort SMEM[32768];  // 64 KB

    const ushort* KVb = KV + (size_t)b * 2048 * 256;
    const ushort* Vtb = Vt + (size_t)b * 128 * 2048;
    const float C2 = 0.12751763f;       // (1/sqrt(128)) * log2(e)
    const float mC = 32.0f * C2;        // fixed max (raw units)

    auto stageK = [&](int buf, int par, int t) {
        ushort* dst = SMEM + (buf * 2 + par) * 4096;
        const int kvb = t * 32;
#pragma unroll
        for (int i = 0; i < 8; ++i) {
            int G = i * 64 + lane;
            int r = G >> 4, gc = G & 15;
            int sgc = gc ^ (r & 15);
            __builtin_amdgcn_global_load_lds(
                (const AS1 void*)(KVb + (size_t)(kvb + r) * 256 + sgc * 8),
                (AS3 void*)(dst + i * 512), 16, 0, 0);
        }
    };
    auto stageV = [&](int buf, int par, int t) {
        ushort* dst = SMEM + 16384 + (buf * 2 + par) * 4096;
        const int kvb = t * 32;
#pragma unroll
        for (int i = 0; i < 8; ++i) {
            int G = i * 64 + lane;
            int g = G >> 3, s = G & 7;
            int u = s ^ (g & 7);
            int r = 2 * g + (u & 1);
            int cc = u >> 1;
            __builtin_amdgcn_global_load_lds(
                (const AS1 void*)(Vtb + (size_t)r * 2048 + kvb + cc * 8),
                (AS3 void*)(dst + G * 8), 16, 0, 0);
        }
    };

#pragma unroll 1
    for (int phase = 0; phase < 2; ++phase) {
        const int tile  = phase ? (63 - a) : a;
        const int qtile = tile * 32;
        const int U = tile + 1;
        const int S = (U + 1) >> 1;
        const size_t qrow = (size_t)(b * 2048 + qtile + c31);

        bf16x8 qf[8];
#pragma unroll
        for (int dk = 0; dk < 8; ++dk)
            qf[dk] = *(const bf16x8*)(Q + qrow * 2048 + h * 128 + dk * 16 + H * 8);

        float l_run = 0.f;
        f32x16 of[4];
#pragma unroll
        for (int dt = 0; dt < 4; ++dt)
#pragma unroll
            for (int r = 0; r < 16; ++r) of[dt][r] = 0.f;

        {
            int t = p;
            if (t < U) { if (wid < 2) stageK(0, p, t); else stageV(0, p, t); }
        }
        __syncthreads();

#pragma unroll 1
        for (int s = 0; s < S; ++s) {
            if (s + 1 < S) {
                int tn = 2 * (s + 1) + p;
                if (tn < U) { if (wid < 2) stageK((s + 1) & 1, p, tn); else stageV((s + 1) & 1, p, tn); }
            }
            const int t = 2 * s + p;
            if (t < U) {
                const ushort* Kb = SMEM + ((s & 1) * 2 + p) * 4096;
                const ushort* Vb = SMEM + 16384 + ((s & 1) * 2 + p) * 4096;
                const bool maskt = (t == tile);

                f32x16 sg = {0,0,0,0,0,0,0,0,0,0,0,0,0,0,0,0};
                __builtin_amdgcn_s_setprio(1);
#pragma unroll
                for (int dk = 0; dk < 8; ++dk) {
                    bf16x8 kf = *(const bf16x8*)(Kb + c31 * 128 + ((dk * 16 + H * 8) ^ ((c31 & 15) << 3)));
                    sg = __builtin_amdgcn_mfma_f32_32x32x16_bf16(kf, qf[dk], sg, 0, 0, 0);
                }
                __builtin_amdgcn_s_setprio(0);

                float e[16];
#pragma unroll
                for (int r = 0; r < 16; ++r) {
                    float v = sg[r];
                    if (maskt) {
                        int crow = (r & 3) + 8 * (r >> 2) + 4 * H;
                        if (crow > c31) v = -1e30f;
                    }
                    e[r] = __builtin_amdgcn_exp2f(__builtin_fmaf(v, C2, -mC));
                }
                float rsum = 0.f;
#pragma unroll
                for (int r = 0; r < 16; ++r) rsum += e[r];
                rsum += __shfl_xor(rsum, 32);
                l_run += rsum;

                unsigned pk[8];
#pragma unroll
                for (int i = 0; i < 8; ++i)
                    asm("v_cvt_pk_bf16_f32 %0, %1, %2" : "=v"(pk[i]) : "v"(e[2 * i]), "v"(e[2 * i + 1]));
                asm("v_permlane32_swap_b32 %0, %1" : "+v"(pk[0]), "+v"(pk[2]));
                asm("v_permlane32_swap_b32 %0, %1" : "+v"(pk[1]), "+v"(pk[3]));
                asm("v_permlane32_swap_b32 %0, %1" : "+v"(pk[4]), "+v"(pk[6]));
                asm("v_permlane32_swap_b32 %0, %1" : "+v"(pk[5]), "+v"(pk[7]));
                union { unsigned u[4]; bf16x8 v; } P0, P1;
                P0.u[0] = pk[0]; P0.u[1] = pk[1]; P0.u[2] = pk[2]; P0.u[3] = pk[3];
                P1.u[0] = pk[4]; P1.u[1] = pk[5]; P1.u[2] = pk[6]; P1.u[3] = pk[7];

                __builtin_amdgcn_s_setprio(1);
#pragma unroll
                for (int dt = 0; dt < 4; ++dt) {
                    int g  = dt * 16 + (c31 >> 1);
                    int sw = g & 7;
                    int b0 = c31 & 1;
                    int s0 = (2 * H + b0) ^ sw;
                    int s1 = (4 + 2 * H + b0) ^ sw;
                    bf16x8 v0 = *(const bf16x8*)(Vb + (g * 8 + s0) * 8);
                    bf16x8 v1 = *(const bf16x8*)(Vb + (g * 8 + s1) * 8);
                    of[dt] = __builtin_amdgcn_mfma_f32_32x32x16_bf16(v0, P0.v, of[dt], 0, 0, 0);
                    of[dt] = __builtin_amdgcn_mfma_f32_32x32x16_bf16(v1, P1.v, of[dt], 0, 0, 0);
                }
                __builtin_amdgcn_s_setprio(0);
            }
            __syncthreads();
        }

        // ---- merge kv-parities (fixed m -> l's simply add) ----
        float* mlb = (float*)SMEM;
        if (H == 0) mlb[wid * 32 + c31] = l_run;
        __syncthreads();
        {
            float lo = mlb[(wid ^ 1) * 32 + c31];
            float inv = 1.0f / (l_run + lo);
            float* ob = (float*)(SMEM + 512) + (wid >> 1) * 4096;
            if (p == 1) {
#pragma unroll
                for (int dt = 0; dt < 4; ++dt)
#pragma unroll
                    for (int rq = 0; rq < 4; ++rq) {
                        f32x4 w;
#pragma unroll
                        for (int j = 0; j < 4; ++j) w[j] = of[dt][rq * 4 + j];
                        *(f32x4*)(ob + ((dt * 4 + rq) * 64 + lane) * 4) = w;
                    }
            }
            __syncthreads();
            if (p == 0) {
                ushort* Orow = O + qrow * 2048 + h * 128;
#pragma unroll
                for (int dt = 0; dt < 4; ++dt)
#pragma unroll
                    for (int rq = 0; rq < 4; ++rq) {
                        f32x4 r4 = *(const f32x4*)(ob + ((dt * 4 + rq) * 64 + lane) * 4);
                        u16x4 o4;
#pragma unroll
                        for (int j = 0; j < 4; ++j)
                            o4[j] = f2b((of[dt][rq * 4 + j] + r4[j]) * inv);
                        int d0 = dt * 32 + rq * 8 + 4 * H;
                        *(u16x4*)(Orow + d0) = o4;
                    }
            }
        }
        __syncthreads();
    }
}

extern "C" void kernel_launch(void* const* d_in, const int* in_sizes, int n_in,
                              void* d_out, int out_size, void* d_ws, size_t ws_size,
                              hipStream_t stream) {
    const float* x   = (const float*)d_in[0];
    const float* Wq  = (const float*)d_in[1];
    const float* Wkv = (const float*)d_in[2];
    const float* Wo  = (const float*)d_in[3];

    char* ws = (char*)d_ws;
    ushort* xb    = (ushort*)(ws);             // [4096][2048] bf16 (16 MB); reused as aob after gemm_qkv
    ushort* wqkvb = (ushort*)(ws + 16777216);  // [2304][2048] (18 MB)
    ushort* wob   = (ushort*)(ws + 35651584);  // [2048][2048] (8 MB)
    ushort* qb    = (ushort*)(ws + 44040192);  // [4096][2048] (16 MB)
    ushort* kvb   = (ushort*)(ws + 60817408);  // [4096][256]  (2 MB, K half used)
    ushort* vtb   = (ushort*)(ws + 62914560);  // [2][128][2048] (1 MB)
    ushort* aob   = xb;                        // attn output aliases xb

    cvt_all<<<2048, 256, 0, stream>>>(x, Wq, Wkv, Wo, xb, wqkvb, wob);

    gemm_qkv<<<576, 512, 0, stream>>>(xb, wqkvb, qb, kvb, vtb, 4096, 2048);
    mqa_attn12<<<512, 256, 0, stream>>>(qb, kvb, vtb, aob);
    gemm_bt<true><<<512, 512, 0, stream>>>(aob, wob, d_out, 4096, 2048, 2048);
}